// Round 2
// baseline (655.812 us; speedup 1.0000x reference)
//
#include <hip/hip_runtime.h>
#include <stdint.h>

typedef unsigned long long u64;
typedef unsigned int u32;

#define THREADS 256
#define CAP 1024
#define NBINS 512
#define LOG_CUT (-230.0f)
#define LOG_SCALE 20.0f

// One workgroup per batch row. LDS: usage[M] + key[CAP] + hist + misc ~ 78KB -> 2 WG/CU.
__global__ __launch_bounds__(THREADS, 2)
void freeness_kernel(const float* __restrict__ ww,    // [B,W,M]
                     const float* __restrict__ fg,    // [B,R]
                     const float* __restrict__ rw,    // [B,R,M]
                     const float* __restrict__ prev,  // [B,M]
                     const float* __restrict__ wgt,   // [B,W]
                     float* __restrict__ out_usage,   // [B,M]
                     float* __restrict__ out_alloc,   // [B,W,M]
                     int W, int R, int M, int num_writes)
{
    extern __shared__ char smem[];
    float* uS  = (float*)smem;                                  // M floats (64KB)
    u64*  keyS = (u64*)(smem + (size_t)M * sizeof(float));      // CAP u64 (8KB)
    u32*  hC   = (u32*)(keyS + CAP);                            // NBINS (2KB)
    float* hL  = (float*)(hC + NBINS);                          // NBINS (2KB)
    int*  misc = (int*)(hL + NBINS);                            // [0]=cand cnt, [1]=cut

    const int b = blockIdx.x;
    const int t = threadIdx.x;
    const int GPT = M / (4 * THREADS);   // granules (float4) per thread

    const float C1 = (float)(1.0 - 1e-6);   // (1-eps) as f32, matches np scalar cast
    const float CE = 1e-6f;

    // ---------- Phase A: usage = (prev + (1-prev)*(1-prod_w(1-ww))) * prod_r(1-fg*rw)
    // op order mirrors the reference expression tree (f32 bit-exact vs np f32)
    for (int k = 0; k < GPT; ++k) {
        const int m = (t + k * THREADS) * 4;
        const float4 pv = *(const float4*)(prev + (size_t)b * M + m);
        float pr0 = 1.f, pr1 = 1.f, pr2 = 1.f, pr3 = 1.f;
        for (int w = 0; w < W; ++w) {
            const float4 a = *(const float4*)(ww + ((size_t)b * W + w) * M + m);
            pr0 *= (1.0f - a.x); pr1 *= (1.0f - a.y);
            pr2 *= (1.0f - a.z); pr3 *= (1.0f - a.w);
        }
        float u0 = pv.x + (1.0f - pv.x) * (1.0f - pr0);
        float u1 = pv.y + (1.0f - pv.y) * (1.0f - pr1);
        float u2 = pv.z + (1.0f - pv.z) * (1.0f - pr2);
        float u3 = pv.w + (1.0f - pv.w) * (1.0f - pr3);
        float f0 = 1.f, f1 = 1.f, f2 = 1.f, f3 = 1.f;
        for (int r = 0; r < R; ++r) {
            const float fr = fg[(size_t)b * R + r];   // wave-uniform -> scalar load
            const float4 a = *(const float4*)(rw + ((size_t)b * R + r) * M + m);
            f0 *= (1.0f - fr * a.x); f1 *= (1.0f - fr * a.y);
            f2 *= (1.0f - fr * a.z); f3 *= (1.0f - fr * a.w);
        }
        float4 uo;
        uo.x = u0 * f0; uo.y = u1 * f1; uo.z = u2 * f2; uo.w = u3 * f3;
        *(float4*)(out_usage + (size_t)b * M + m) = uo;
        *(float4*)(uS + m) = uo;
    }
    __syncthreads();

    // ---------- Phase B: per write head
    for (int i = 0; i < num_writes; ++i) {
        const float wgi = wgt[(size_t)b * W + i];
        float* orow = out_alloc + ((size_t)b * W + i) * M;

        for (int x = t; x < NBINS; x += THREADS) { hC[x] = 0u; hL[x] = 0.0f; }
        if (t == 0) misc[0] = 0;
        __syncthreads();

        // log-domain histogram: bkt = floor(-log2(ue)*20); higher bkt = smaller usage
        for (int k = 0; k < GPT; ++k) {
            const int m = (t + k * THREADS) * 4;
            const float4 uu = *(const float4*)(uS + m);
            const float ua[4] = {uu.x, uu.y, uu.z, uu.w};
            #pragma unroll
            for (int j = 0; j < 4; ++j) {
                const float ue = CE + C1 * ua[j];
                const float lg = __log2f(ue);
                int bkt = (int)(-lg * LOG_SCALE);
                bkt = bkt < 0 ? 0 : (bkt > NBINS - 1 ? NBINS - 1 : bkt);
                atomicAdd(&hC[bkt], 1u);
                atomicAdd(&hL[bkt], lg);
            }
        }
        __syncthreads();

        // cutoff scan HIGH->LOW (smallest usage first): minimal bucket-suffix with
        // cum log2 <= LOG_CUT (=> ref f32 cumprod exactly 0 beyond it), count-capped
        if (t == 0) {
            float cum = 0.0f; u32 cnt = 0; int cut = NBINS;
            for (int x = NBINS - 1; x >= 0; --x) {
                const u32 c2 = cnt + hC[x];
                if (c2 > (u32)CAP) break;
                cnt = c2; cum += hL[x]; cut = x;
                if (cum <= LOG_CUT) break;
            }
            misc[1] = cut;
        }
        __syncthreads();
        const int cut = misc[1];

        // zero-fill output row + compact candidate keys (bkt >= cut)
        // key = (~bits(fl(1-ue)) << 14) | idx -> ascending == nonusage desc, idx tiebreak
        for (int k = 0; k < GPT; ++k) {
            const int m = (t + k * THREADS) * 4;
            *(float4*)(orow + m) = make_float4(0.f, 0.f, 0.f, 0.f);
            const float4 uu = *(const float4*)(uS + m);
            const float ua[4] = {uu.x, uu.y, uu.z, uu.w};
            #pragma unroll
            for (int j = 0; j < 4; ++j) {
                const float ue = CE + C1 * ua[j];
                const float lg = __log2f(ue);
                int bkt = (int)(-lg * LOG_SCALE);
                bkt = bkt < 0 ? 0 : (bkt > NBINS - 1 ? NBINS - 1 : bkt);
                if (bkt >= cut) {
                    const int pos = atomicAdd(&misc[0], 1);
                    if (pos < CAP) {
                        const float nn = 1.0f - ue;       // nonusage, exactly as ref
                        const u32 nb = ~__float_as_uint(nn);
                        keyS[pos] = (((u64)nb) << 14) | (u64)(u32)(m + j);
                    }
                }
            }
        }
        __syncthreads();
        int K = misc[0]; if (K > CAP) K = CAP;

        for (int x = K + t; x < CAP; x += THREADS) keyS[x] = ~0ull;
        __syncthreads();

        // bitonic sort of CAP u64 keys (ascending)
        for (u32 kk = 2; kk <= (u32)CAP; kk <<= 1) {
            for (u32 jj = kk >> 1; jj > 0; jj >>= 1) {
                for (u32 x = t; x < (u32)CAP; x += THREADS) {
                    const u32 l = x ^ jj;
                    if (l > x) {
                        const u64 a = keyS[x];
                        const u64 c = keyS[l];
                        const bool up = ((x & kk) == 0u);
                        if ((a > c) == up) { keyS[x] = c; keyS[l] = a; }
                    }
                }
                __syncthreads();
            }
        }

        // serial exclusive f32 cumprod over sorted candidates (bit-exact np.cumprod),
        // scatter nonzero allocs, update usage in LDS; break once P hits exact 0
        if (t == 0) {
            float P = 1.0f;
            for (int x = 0; x < K; ++x) {
                const u64 key = keyS[x];
                const u32 nb = ~((u32)(key >> 14));
                const float nn = __uint_as_float(nb);      // sorted_nonusage
                const int idx = (int)(key & 0x3FFFull);
                const float al = nn * P;                   // sorted_allocation
                if (al != 0.0f) orow[idx] = al;
                const float u0 = uS[idx];
                uS[idx] = u0 + ((1.0f - u0) * wgi) * al;   // usage += (1-usage)*wg*a
                P = P * (1.0f - nn);                       // cumprod of sorted_usage
                if (P == 0.0f) break;
            }
        }
        __syncthreads();
    }
}

extern "C" void kernel_launch(void* const* d_in, const int* in_sizes, int n_in,
                              void* d_out, int out_size, void* d_ws, size_t ws_size,
                              hipStream_t stream) {
    const float* ww   = (const float*)d_in[0];
    const float* fg   = (const float*)d_in[1];
    const float* rw   = (const float*)d_in[2];
    const float* prev = (const float*)d_in[3];
    const float* wgt  = (const float*)d_in[4];
    const int BWM = in_sizes[0];
    const int BR  = in_sizes[1];
    const int BM  = in_sizes[3];
    const int BW  = in_sizes[4];
    const int M = BWM / BW;
    const int B = BM / M;
    const int W = BW / B;
    const int R = BR / B;

    float* out_usage = (float*)d_out;
    float* out_alloc = out_usage + (size_t)BM;

    const size_t smem = (size_t)M * sizeof(float) + (size_t)CAP * 8
                        + (size_t)NBINS * 8 + 256;

    hipLaunchKernelGGL(freeness_kernel, dim3(B), dim3(THREADS), smem, stream,
                       ww, fg, rw, prev, wgt, out_usage, out_alloc,
                       W, R, M, /*num_writes=*/W);
}

// Round 3
// 544.943 us; speedup vs baseline: 1.2034x; 1.2034x over previous
//
#include <hip/hip_runtime.h>
#include <stdint.h>

typedef unsigned long long u64;
typedef unsigned int u32;

#define NBINS 512
#define CAP 1024
#define LOG_CUT (-230.0f)
#define LOG_SCALE 20.0f

// ---------------- Kernel 1: streaming usage + zero-fill alloc ----------------
// usage = (prev + (1-prev)*(1-prod_w(1-ww))) * prod_r(1-fg*rw), bit-exact f32
template <int TW, int TR>
__global__ __launch_bounds__(256)
void phaseA_kernel(const float* __restrict__ ww, const float* __restrict__ fg,
                   const float* __restrict__ rw, const float* __restrict__ prev,
                   float* __restrict__ out_usage, float* __restrict__ out_alloc,
                   int B, int W, int R, int M)
{
    const int Wl = TW > 0 ? TW : W;
    const int Rl = TR > 0 ? TR : R;
    const int g4 = M >> 2;
    const long long total = (long long)B * g4;
    const long long stride = (long long)gridDim.x * blockDim.x;
    for (long long g = (long long)blockIdx.x * blockDim.x + threadIdx.x; g < total; g += stride) {
        const int b = (int)(g / g4);
        const int m = ((int)(g % g4)) << 2;
        const size_t bM = (size_t)b * M + m;
        const float4 pv = *(const float4*)(prev + bM);
        float pr0 = 1.f, pr1 = 1.f, pr2 = 1.f, pr3 = 1.f;
        #pragma unroll
        for (int w = 0; w < Wl; ++w) {
            const float4 a = *(const float4*)(ww + ((size_t)b * Wl + w) * M + m);
            pr0 *= (1.0f - a.x); pr1 *= (1.0f - a.y);
            pr2 *= (1.0f - a.z); pr3 *= (1.0f - a.w);
        }
        float u0 = pv.x + (1.0f - pv.x) * (1.0f - pr0);
        float u1 = pv.y + (1.0f - pv.y) * (1.0f - pr1);
        float u2 = pv.z + (1.0f - pv.z) * (1.0f - pr2);
        float u3 = pv.w + (1.0f - pv.w) * (1.0f - pr3);
        float f0 = 1.f, f1 = 1.f, f2 = 1.f, f3 = 1.f;
        #pragma unroll
        for (int r = 0; r < Rl; ++r) {
            const float fr = fg[(size_t)b * Rl + r];
            const float4 a = *(const float4*)(rw + ((size_t)b * Rl + r) * M + m);
            f0 *= (1.0f - fr * a.x); f1 *= (1.0f - fr * a.y);
            f2 *= (1.0f - fr * a.z); f3 *= (1.0f - fr * a.w);
        }
        float4 uo;
        uo.x = u0 * f0; uo.y = u1 * f1; uo.z = u2 * f2; uo.w = u3 * f3;
        *(float4*)(out_usage + bM) = uo;
        const float4 z = make_float4(0.f, 0.f, 0.f, 0.f);
        #pragma unroll
        for (int w = 0; w < Wl; ++w)
            *(float4*)(out_alloc + ((size_t)b * Wl + w) * M + m) = z;
    }
}

// ---------------- Kernel 2: per-row allocation (latency-optimized) ----------------
__global__ __launch_bounds__(512, 2)
void phaseB_kernel(const float* __restrict__ wgt,
                   const float* __restrict__ usage_in,   // [B,M] (kernel 1 output)
                   float* __restrict__ out_alloc,        // [B,W,M] (pre-zeroed)
                   int B, int W, int M)
{
    extern __shared__ char smem[];
    float* uS  = (float*)smem;                               // M floats
    u64*  keyS = (u64*)(smem + (size_t)M * sizeof(float));   // CAP u64
    u32*  hC   = (u32*)(keyS + CAP);                         // NBINS
    float* hL  = (float*)(hC + NBINS);                       // NBINS
    int*  misc = (int*)(hL + NBINS);                         // [0]=count, [1]=cut

    const int b = blockIdx.x;
    const int t = threadIdx.x;
    const int lane = t & 63;
    const int wid = t >> 6;
    const int NT = blockDim.x;

    const float C1 = (float)(1.0 - 1e-6);
    const float CE = 1e-6f;

    // load usage row into LDS
    for (int x = t * 4; x < M; x += NT * 4)
        *(float4*)(uS + x) = *(const float4*)(usage_in + (size_t)b * M + x);
    __syncthreads();

    for (int i = 0; i < W; ++i) {
        const float wgi = wgt[(size_t)b * W + i];
        float* orow = out_alloc + ((size_t)b * W + i) * M;

        for (int x = t; x < NBINS; x += NT) { hC[x] = 0u; hL[x] = 0.0f; }
        if (t == 0) misc[0] = 0;
        __syncthreads();

        // log-domain histogram (bkt = floor(-log2(ue)*20); higher bkt = smaller usage)
        for (int x = t * 4; x < M; x += NT * 4) {
            const float4 uu = *(const float4*)(uS + x);
            const float ua[4] = {uu.x, uu.y, uu.z, uu.w};
            #pragma unroll
            for (int j = 0; j < 4; ++j) {
                const float ue = CE + C1 * ua[j];
                const float lg = __log2f(ue);
                int bkt = (int)(-lg * LOG_SCALE);
                bkt = bkt < 0 ? 0 : (bkt > NBINS - 1 ? NBINS - 1 : bkt);
                atomicAdd(&hC[bkt], 1u);
                atomicAdd(&hL[bkt], lg);
            }
        }
        __syncthreads();

        // cutoff scan high->low: stop at cum<=LOG_CUT (ref cumprod exactly 0 beyond)
        // or before count exceeds CAP (=> candidate count always <= CAP, no drops)
        if (t == 0) {
            float cum = 0.0f; u32 cnt = 0; int cut = NBINS;
            for (int x = NBINS - 1; x >= 0; --x) {
                const u32 c2 = cnt + hC[x];
                if (c2 > (u32)CAP) break;
                cnt = c2; cum += hL[x]; cut = x;
                if (cum <= LOG_CUT) break;
            }
            misc[1] = cut;
        }
        __syncthreads();
        const int cut = misc[1];

        // compact candidates: key = (~bits(1-ue) << 14) | idx
        // ascending sort == nonusage desc with lower-index tiebreak (== lax.top_k)
        for (int x = t * 4; x < M; x += NT * 4) {
            const float4 uu = *(const float4*)(uS + x);
            const float ua[4] = {uu.x, uu.y, uu.z, uu.w};
            #pragma unroll
            for (int j = 0; j < 4; ++j) {
                const float ue = CE + C1 * ua[j];
                const float lg = __log2f(ue);
                int bkt = (int)(-lg * LOG_SCALE);
                bkt = bkt < 0 ? 0 : (bkt > NBINS - 1 ? NBINS - 1 : bkt);
                if (bkt >= cut) {
                    const int pos = atomicAdd(&misc[0], 1);
                    if (pos < CAP) {
                        const float nn = 1.0f - ue;
                        keyS[pos] = (((u64)(~__float_as_uint(nn))) << 14) | (u64)(u32)(x + j);
                    }
                }
            }
        }
        __syncthreads();
        int K = misc[0]; if (K > CAP) K = CAP;
        int P2 = 64; while (P2 < K) P2 <<= 1;     // uniform across block

        for (int x = K + t; x < P2; x += NT) keyS[x] = ~0ull;   // pad: sorts last
        __syncthreads();

        // wave-0-only phases: bitonic sort + chunked cumprod (no block barriers inside)
        if (wid == 0) {
            // wave-synchronous LDS bitonic over P2 keys
            const int npair = P2 >> 1;
            for (int kk = 2; kk <= P2; kk <<= 1) {
                for (int jj = kk >> 1; jj > 0; jj >>= 1) {
                    for (int q = lane; q < npair; q += 64) {
                        const int x = ((q & ~(jj - 1)) << 1) | (q & (jj - 1));
                        const int y = x | jj;
                        const u64 a = keyS[x];
                        const u64 c = keyS[y];
                        const bool up = ((x & kk) == 0);
                        if ((a > c) == up) { keyS[x] = c; keyS[y] = a; }
                    }
                    // intra-wave pass ordering (DS in-order per wave; belt & braces)
                    asm volatile("s_waitcnt lgkmcnt(0)" ::: "memory");
                }
            }

            // chunked exclusive cumprod: lane l owns ranks [l*CHUNK, (l+1)*CHUNK)
            const int CHUNK = P2 >> 6;   // >= 1
            const int base = lane * CHUNK;
            float Q = 1.0f;
            for (int c = 0; c < CHUNK; ++c) {
                const u64 key = keyS[base + c];
                const float nn = __uint_as_float(~((u32)(key >> 14)));
                Q *= (1.0f - nn);
            }
            // inclusive scan of chunk products, then shift for exclusive prefix
            float S = Q;
            #pragma unroll
            for (int off = 1; off < 64; off <<= 1) {
                const float o = __shfl_up(S, off);
                if (lane >= off) S *= o;
            }
            float P = __shfl_up(S, 1);
            if (lane == 0) P = 1.0f;
            // scatter allocations + usage update (distinct idx per candidate)
            for (int c = 0; c < CHUNK; ++c) {
                const u64 key = keyS[base + c];
                const float nn = __uint_as_float(~((u32)(key >> 14)));
                const int idx = (int)(key & 0x3FFFull);
                const float al = nn * P;
                if (al != 0.0f) {
                    orow[idx] = al;                       // row pre-zeroed by kernel 1
                    const float u0v = uS[idx];
                    uS[idx] = u0v + ((1.0f - u0v) * wgi) * al;
                }
                P *= (1.0f - nn);
            }
            asm volatile("s_waitcnt lgkmcnt(0)" ::: "memory");
        }
        __syncthreads();
    }
}

extern "C" void kernel_launch(void* const* d_in, const int* in_sizes, int n_in,
                              void* d_out, int out_size, void* d_ws, size_t ws_size,
                              hipStream_t stream) {
    const float* ww   = (const float*)d_in[0];
    const float* fg   = (const float*)d_in[1];
    const float* rw   = (const float*)d_in[2];
    const float* prev = (const float*)d_in[3];
    const float* wgt  = (const float*)d_in[4];
    const int BWM = in_sizes[0];
    const int BR  = in_sizes[1];
    const int BM  = in_sizes[3];
    const int BW  = in_sizes[4];
    const int M = BWM / BW;
    const int B = BM / M;
    const int W = BW / B;
    const int R = BR / B;

    float* out_usage = (float*)d_out;
    float* out_alloc = out_usage + (size_t)BM;

    // kernel 1: streaming, high occupancy
    const long long granules = (long long)B * (M >> 2);
    int blocks = (int)((granules + 255) / 256);
    if (blocks > 2048) blocks = 2048;
    if (W == 4 && R == 8) {
        hipLaunchKernelGGL((phaseA_kernel<4, 8>), dim3(blocks), dim3(256), 0, stream,
                           ww, fg, rw, prev, out_usage, out_alloc, B, W, R, M);
    } else {
        hipLaunchKernelGGL((phaseA_kernel<0, 0>), dim3(blocks), dim3(256), 0, stream,
                           ww, fg, rw, prev, out_usage, out_alloc, B, W, R, M);
    }

    // kernel 2: per-row allocation
    const size_t smem = (size_t)M * sizeof(float) + (size_t)CAP * 8
                        + (size_t)NBINS * 8 + 64;
    hipLaunchKernelGGL(phaseB_kernel, dim3(B), dim3(512), smem, stream,
                       wgt, out_usage, out_alloc, B, W, M);
}

// Round 4
// 180.537 us; speedup vs baseline: 3.6326x; 3.0185x over previous
//
#include <hip/hip_runtime.h>
#include <stdint.h>

typedef unsigned long long u64;
typedef unsigned int u32;

#define NBINS 512
#define CAP 512
#define LOG_CUT (-64.0f)
#define LOG_SCALE 20.0f
#define NT 512

// ---------------- Kernel 1: streaming usage + zero-fill alloc ----------------
// usage = (prev + (1-prev)*(1-prod_w(1-ww))) * prod_r(1-fg*rw), bit-exact f32
template <int TW, int TR>
__global__ __launch_bounds__(256)
void phaseA_kernel(const float* __restrict__ ww, const float* __restrict__ fg,
                   const float* __restrict__ rw, const float* __restrict__ prev,
                   float* __restrict__ out_usage, float* __restrict__ out_alloc,
                   int B, int W, int R, int M)
{
    const int Wl = TW > 0 ? TW : W;
    const int Rl = TR > 0 ? TR : R;
    const int g4 = M >> 2;
    const long long total = (long long)B * g4;
    const long long stride = (long long)gridDim.x * blockDim.x;
    for (long long g = (long long)blockIdx.x * blockDim.x + threadIdx.x; g < total; g += stride) {
        const int b = (int)(g / g4);
        const int m = ((int)(g % g4)) << 2;
        const size_t bM = (size_t)b * M + m;
        const float4 pv = *(const float4*)(prev + bM);
        float pr0 = 1.f, pr1 = 1.f, pr2 = 1.f, pr3 = 1.f;
        #pragma unroll
        for (int w = 0; w < Wl; ++w) {
            const float4 a = *(const float4*)(ww + ((size_t)b * Wl + w) * M + m);
            pr0 *= (1.0f - a.x); pr1 *= (1.0f - a.y);
            pr2 *= (1.0f - a.z); pr3 *= (1.0f - a.w);
        }
        float u0 = pv.x + (1.0f - pv.x) * (1.0f - pr0);
        float u1 = pv.y + (1.0f - pv.y) * (1.0f - pr1);
        float u2 = pv.z + (1.0f - pv.z) * (1.0f - pr2);
        float u3 = pv.w + (1.0f - pv.w) * (1.0f - pr3);
        float f0 = 1.f, f1 = 1.f, f2 = 1.f, f3 = 1.f;
        #pragma unroll
        for (int r = 0; r < Rl; ++r) {
            const float fr = fg[(size_t)b * Rl + r];
            const float4 a = *(const float4*)(rw + ((size_t)b * Rl + r) * M + m);
            f0 *= (1.0f - fr * a.x); f1 *= (1.0f - fr * a.y);
            f2 *= (1.0f - fr * a.z); f3 *= (1.0f - fr * a.w);
        }
        float4 uo;
        uo.x = u0 * f0; uo.y = u1 * f1; uo.z = u2 * f2; uo.w = u3 * f3;
        *(float4*)(out_usage + bM) = uo;
        const float4 z = make_float4(0.f, 0.f, 0.f, 0.f);
        #pragma unroll
        for (int w = 0; w < Wl; ++w)
            *(float4*)(out_alloc + ((size_t)b * Wl + w) * M + m) = z;
    }
}

// ---------------- Kernel 2: per-row allocation, sort-free ----------------
// Rank via O(K^2) pairwise key compares (K<=512); P via exp2(sum log2) --
// abs error ~1e-3 << 0.02 threshold. No sort, no serial sections.
__global__ __launch_bounds__(NT, 2)
void phaseB_kernel(const float* __restrict__ wgt,
                   const float* __restrict__ usage_in,   // [B,M]
                   float* __restrict__ out_alloc,        // [B,W,M] pre-zeroed
                   int B, int W, int M)
{
    __shared__ u64  keyS[CAP];
    __shared__ float logS[CAP];
    __shared__ u32  hC[NBINS];
    __shared__ u32  tc[8];
    __shared__ float tw[8];
    __shared__ int  misc[4];   // [0]=cand count, [1]=max xs, [2]=min xc
    extern __shared__ float uS[];                        // M floats

    const int b = blockIdx.x;
    const int t = threadIdx.x;
    const int lane = t & 63;
    const int wid = t >> 6;

    const float C1 = (float)(1.0 - 1e-6);
    const float CE = 1e-6f;

    // load usage row into LDS
    for (int x = t * 4; x < M; x += NT * 4)
        *(float4*)(uS + x) = *(const float4*)(usage_in + (size_t)b * M + x);

    for (int i = 0; i < W; ++i) {
        const float wgi = wgt[(size_t)b * W + i];
        float* orow = out_alloc + ((size_t)b * W + i) * M;

        // init histogram + misc (also serves as the post-load/post-update barrier)
        hC[t] = 0u;
        if (t == 0) { misc[0] = 0; misc[1] = -1; misc[2] = NBINS; }
        __syncthreads();

        // count-only log-domain histogram: bkt = floor(-log2(ue)*20)
        for (int x = t * 4; x < M; x += NT * 4) {
            const float4 uu = *(const float4*)(uS + x);
            const float ua[4] = {uu.x, uu.y, uu.z, uu.w};
            #pragma unroll
            for (int j = 0; j < 4; ++j) {
                const float ue = CE + C1 * ua[j];
                const float lg = __log2f(ue);
                int bkt = (int)(-lg * LOG_SCALE);
                bkt = bkt < 0 ? 0 : (bkt > NBINS - 1 ? NBINS - 1 : bkt);
                atomicAdd(&hC[bkt], 1u);
            }
        }
        __syncthreads();

        // parallel suffix scan over buckets (reversed order): thread t owns x=511-t
        // Sc = suffix count C(x); Sw = conservative log bound (each elem in bkt y
        // has log2(ue) <= -y/20, so Sw >= true sum; Sw<=LOG_CUT => true<=LOG_CUT)
        {
            const int x = NBINS - 1 - t;
            const u32 c = hC[x];
            u32 sc = c;
            float sw = -(float)x * (1.0f / LOG_SCALE) * (float)c;
            #pragma unroll
            for (int off = 1; off < 64; off <<= 1) {
                const u32  oc = __shfl_up(sc, off);
                const float ow = __shfl_up(sw, off);
                if (lane >= off) { sc += oc; sw += ow; }
            }
            if (lane == 63) { tc[wid] = sc; tw[wid] = sw; }
            __syncthreads();
            u32 ac = 0; float aw = 0.f;
            for (int q = 0; q < wid; ++q) { ac += tc[q]; aw += tw[q]; }
            sc += ac; sw += aw;
            if (sw <= LOG_CUT) atomicMax(&misc[1], x);   // xs: max x with enough mass
            if (sc <= (u32)CAP) atomicMin(&misc[2], x);  // xc: min x within count cap
        }
        __syncthreads();
        const int xs = misc[1];
        const int xc = misc[2];
        const int cut = (xs > xc) ? xs : xc;             // xs=-1 -> xc; xc=NBINS -> K=0

        // compact candidates (bkt >= cut) with wave-aggregated counter
        for (int x = t; x < M; x += NT) {
            const float u = uS[x];
            const float ue = CE + C1 * u;
            const float lg = __log2f(ue);
            int bkt = (int)(-lg * LOG_SCALE);
            bkt = bkt < 0 ? 0 : (bkt > NBINS - 1 ? NBINS - 1 : bkt);
            const bool pred = (bkt >= cut) && (cut < NBINS);
            const u64 mask = __ballot(pred);
            const int cnt = __popcll(mask);
            if (cnt) {
                int base = 0;
                if (lane == 0) base = atomicAdd(&misc[0], cnt);
                base = __shfl(base, 0);
                if (pred) {
                    const int pos = base + __popcll(mask & ((1ull << lane) - 1));
                    if (pos < CAP) {
                        const float nn = 1.0f - ue;      // nonusage, exactly as ref
                        keyS[pos] = (((u64)(~__float_as_uint(nn))) << 14) | (u64)(u32)x;
                        logS[pos] = lg;
                    }
                }
            }
        }
        __syncthreads();
        int K = misc[0]; if (K > CAP) K = CAP;

        // pairwise rank: S_t = sum of log2(ue_k) over keys strictly smaller.
        // key asc == nonusage desc with lower-index tiebreak (== lax.top_k order).
        if (t < K) {
            const u64 mykey = keyS[t];
            float S = 0.0f;
            #pragma unroll 4
            for (int k = 0; k < K; ++k) {
                const u64 kk = keyS[k];      // LDS broadcast
                const float lg = logS[k];
                if (kk < mykey) S += lg;
            }
            const float nn = __uint_as_float(~((u32)(mykey >> 14)));
            const int idx = (int)(mykey & 0x3FFFull);
            const float al = nn * __builtin_exp2f(S);
            if (al != 0.0f) {
                orow[idx] = al;                          // row pre-zeroed by kernel 1
                const float u0v = uS[idx];
                uS[idx] = u0v + ((1.0f - u0v) * wgi) * al;
            }
        }
        __syncthreads();
    }
}

extern "C" void kernel_launch(void* const* d_in, const int* in_sizes, int n_in,
                              void* d_out, int out_size, void* d_ws, size_t ws_size,
                              hipStream_t stream) {
    const float* ww   = (const float*)d_in[0];
    const float* fg   = (const float*)d_in[1];
    const float* rw   = (const float*)d_in[2];
    const float* prev = (const float*)d_in[3];
    const float* wgt  = (const float*)d_in[4];
    const int BWM = in_sizes[0];
    const int BR  = in_sizes[1];
    const int BM  = in_sizes[3];
    const int BW  = in_sizes[4];
    const int M = BWM / BW;
    const int B = BM / M;
    const int W = BW / B;
    const int R = BR / B;

    float* out_usage = (float*)d_out;
    float* out_alloc = out_usage + (size_t)BM;

    const long long granules = (long long)B * (M >> 2);
    int blocks = (int)((granules + 255) / 256);
    if (blocks > 2048) blocks = 2048;
    if (W == 4 && R == 8) {
        hipLaunchKernelGGL((phaseA_kernel<4, 8>), dim3(blocks), dim3(256), 0, stream,
                           ww, fg, rw, prev, out_usage, out_alloc, B, W, R, M);
    } else {
        hipLaunchKernelGGL((phaseA_kernel<0, 0>), dim3(blocks), dim3(256), 0, stream,
                           ww, fg, rw, prev, out_usage, out_alloc, B, W, R, M);
    }

    const size_t smem = (size_t)M * sizeof(float);   // dynamic part: uS only
    hipLaunchKernelGGL(phaseB_kernel, dim3(B), dim3(NT), smem, stream,
                       wgt, out_usage, out_alloc, B, W, M);
}

// Round 5
// 163.212 us; speedup vs baseline: 4.0181x; 1.1061x over previous
//
#include <hip/hip_runtime.h>
#include <stdint.h>

typedef unsigned long long u64;
typedef unsigned int u32;

#define NBINS 512
#define CAP 512
#define LOG_CUT (-64.0f)
#define LOG_SCALE 20.0f
#define NT 512

// One fused kernel: one workgroup per batch row.
// Phase S: stream inputs -> usage (bit-exact f32) -> LDS + global; zero-fill alloc rows.
// Phase H (x W heads): log-histogram -> parallel suffix scan -> ballot compact ->
//                      O(K^2) pairwise rank -> alloc scatter + usage update in LDS.
// LDS: uS 64KB dyn + keyS 4KB + logS 2KB + hC 2KB + misc -> ~72.3KB => 2 blocks/CU.
template <int TW, int TR>
__global__ __launch_bounds__(NT, 4)
void fused_kernel(const float* __restrict__ ww,    // [B,W,M]
                  const float* __restrict__ fg,    // [B,R]
                  const float* __restrict__ rw,    // [B,R,M]
                  const float* __restrict__ prev,  // [B,M]
                  const float* __restrict__ wgt,   // [B,W]
                  float* __restrict__ out_usage,   // [B,M]
                  float* __restrict__ out_alloc,   // [B,W,M]
                  int B, int W, int R, int M)
{
    __shared__ u64   keyS[CAP];
    __shared__ float logS[CAP];
    __shared__ u32   hC[NBINS];
    __shared__ u32   tc[8];
    __shared__ float tw[8];
    __shared__ int   misc[4];   // [0]=cand count, [1]=max xs, [2]=min xc
    extern __shared__ float uS[];                  // M floats

    const int Wl = TW > 0 ? TW : W;
    const int Rl = TR > 0 ? TR : R;
    const int b = blockIdx.x;
    const int t = threadIdx.x;
    const int lane = t & 63;
    const int wid = t >> 6;

    const float C1 = (float)(1.0 - 1e-6);
    const float CE = 1e-6f;

    // ---------------- Phase S: streaming ----------------
    // usage = (prev + (1-prev)*(1-prod_w(1-ww))) * prod_r(1-fg*rw), ref f32 op order
    {
        const size_t rowOff = (size_t)b * M;
        float frs[TR > 0 ? TR : 8];
        if (TR > 0)
            #pragma unroll
            for (int r = 0; r < Rl; ++r) frs[r] = fg[(size_t)b * Rl + r];

        const float4 z = make_float4(0.f, 0.f, 0.f, 0.f);
        for (int m = t * 4; m < M; m += NT * 4) {
            const float4 pv = *(const float4*)(prev + rowOff + m);
            float pr0 = 1.f, pr1 = 1.f, pr2 = 1.f, pr3 = 1.f;
            #pragma unroll
            for (int w = 0; w < Wl; ++w) {
                const float4 a = *(const float4*)(ww + ((size_t)b * Wl + w) * M + m);
                pr0 *= (1.0f - a.x); pr1 *= (1.0f - a.y);
                pr2 *= (1.0f - a.z); pr3 *= (1.0f - a.w);
            }
            float u0 = pv.x + (1.0f - pv.x) * (1.0f - pr0);
            float u1 = pv.y + (1.0f - pv.y) * (1.0f - pr1);
            float u2 = pv.z + (1.0f - pv.z) * (1.0f - pr2);
            float u3 = pv.w + (1.0f - pv.w) * (1.0f - pr3);
            float f0 = 1.f, f1 = 1.f, f2 = 1.f, f3 = 1.f;
            #pragma unroll
            for (int r = 0; r < Rl; ++r) {
                const float fr = (TR > 0) ? frs[r] : fg[(size_t)b * Rl + r];
                const float4 a = *(const float4*)(rw + ((size_t)b * Rl + r) * M + m);
                f0 *= (1.0f - fr * a.x); f1 *= (1.0f - fr * a.y);
                f2 *= (1.0f - fr * a.z); f3 *= (1.0f - fr * a.w);
            }
            float4 uo;
            uo.x = u0 * f0; uo.y = u1 * f1; uo.z = u2 * f2; uo.w = u3 * f3;
            *(float4*)(uS + m) = uo;
            *(float4*)(out_usage + rowOff + m) = uo;
            #pragma unroll
            for (int w = 0; w < Wl; ++w)
                *(float4*)(out_alloc + ((size_t)b * Wl + w) * M + m) = z;
        }
    }

    // ---------------- Phase H: per write head ----------------
    for (int i = 0; i < Wl; ++i) {
        const float wgi = wgt[(size_t)b * Wl + i];
        float* orow = out_alloc + ((size_t)b * Wl + i) * M;

        hC[t] = 0u;
        if (t == 0) { misc[0] = 0; misc[1] = -1; misc[2] = NBINS; }
        __syncthreads();   // also orders phase-S LDS writes / prior head updates

        // count-only log-domain histogram: bkt = floor(-log2(ue)*20)
        for (int x = t * 4; x < M; x += NT * 4) {
            const float4 uu = *(const float4*)(uS + x);
            const float ua[4] = {uu.x, uu.y, uu.z, uu.w};
            #pragma unroll
            for (int j = 0; j < 4; ++j) {
                const float ue = CE + C1 * ua[j];
                const float lg = __log2f(ue);
                int bkt = (int)(-lg * LOG_SCALE);
                bkt = bkt < 0 ? 0 : (bkt > NBINS - 1 ? NBINS - 1 : bkt);
                atomicAdd(&hC[bkt], 1u);
            }
        }
        __syncthreads();

        // parallel suffix scan over buckets (thread t owns x = 511-t):
        // Sc = suffix count; Sw = conservative log bound (elem in bkt y has
        // log2(ue) <= -y/20 => Sw >= true sum; Sw<=LOG_CUT => true sum <= LOG_CUT)
        {
            const int x = NBINS - 1 - t;
            const u32 c = hC[x];
            u32 sc = c;
            float sw = -(float)x * (1.0f / LOG_SCALE) * (float)c;
            #pragma unroll
            for (int off = 1; off < 64; off <<= 1) {
                const u32  oc = __shfl_up(sc, off);
                const float ow = __shfl_up(sw, off);
                if (lane >= off) { sc += oc; sw += ow; }
            }
            if (lane == 63) { tc[wid] = sc; tw[wid] = sw; }
            __syncthreads();
            u32 ac = 0; float aw = 0.f;
            for (int q = 0; q < wid; ++q) { ac += tc[q]; aw += tw[q]; }
            sc += ac; sw += aw;
            if (sw <= LOG_CUT) atomicMax(&misc[1], x);   // enough log-mass
            if (sc <= (u32)CAP) atomicMin(&misc[2], x);  // within count cap
        }
        __syncthreads();
        const int xs = misc[1];
        const int xc = misc[2];
        const int cut = (xs > xc) ? xs : xc;

        // compact candidates (bkt >= cut), wave-aggregated counter
        // key = (~bits(1-ue) << 14) | idx: asc == nonusage desc, low-idx tiebreak
        for (int x = t; x < M; x += NT) {
            const float u = uS[x];
            const float ue = CE + C1 * u;
            const float lg = __log2f(ue);
            int bkt = (int)(-lg * LOG_SCALE);
            bkt = bkt < 0 ? 0 : (bkt > NBINS - 1 ? NBINS - 1 : bkt);
            const bool pred = (bkt >= cut) && (cut < NBINS);
            const u64 mask = __ballot(pred);
            const int cnt = __popcll(mask);
            if (cnt) {
                int base = 0;
                if (lane == 0) base = atomicAdd(&misc[0], cnt);
                base = __shfl(base, 0);
                if (pred) {
                    const int pos = base + __popcll(mask & ((1ull << lane) - 1));
                    if (pos < CAP) {
                        const float nn = 1.0f - ue;
                        keyS[pos] = (((u64)(~__float_as_uint(nn))) << 14) | (u64)(u32)x;
                        logS[pos] = lg;
                    }
                }
            }
        }
        __syncthreads();
        int K = misc[0]; if (K > CAP) K = CAP;

        // pairwise rank: S_t = sum log2(ue_k) over strictly-smaller keys;
        // alloc = nonusage * exp2(S) (abs err ~1e-3 << 2e-2 threshold)
        if (t < K) {
            const u64 mykey = keyS[t];
            float S = 0.0f;
            #pragma unroll 4
            for (int k = 0; k < K; ++k) {
                const u64 kk = keyS[k];      // LDS broadcast
                const float lg = logS[k];
                if (kk < mykey) S += lg;
            }
            const float nn = __uint_as_float(~((u32)(mykey >> 14)));
            const int idx = (int)(mykey & 0x3FFFull);
            const float al = nn * __builtin_exp2f(S);
            if (al != 0.0f) {
                orow[idx] = al;                          // row pre-zeroed in phase S
                const float u0v = uS[idx];
                uS[idx] = u0v + ((1.0f - u0v) * wgi) * al;
            }
        }
        __syncthreads();
    }
}

extern "C" void kernel_launch(void* const* d_in, const int* in_sizes, int n_in,
                              void* d_out, int out_size, void* d_ws, size_t ws_size,
                              hipStream_t stream) {
    const float* ww   = (const float*)d_in[0];
    const float* fg   = (const float*)d_in[1];
    const float* rw   = (const float*)d_in[2];
    const float* prev = (const float*)d_in[3];
    const float* wgt  = (const float*)d_in[4];
    const int BWM = in_sizes[0];
    const int BR  = in_sizes[1];
    const int BM  = in_sizes[3];
    const int BW  = in_sizes[4];
    const int M = BWM / BW;
    const int B = BM / M;
    const int W = BW / B;
    const int R = BR / B;

    float* out_usage = (float*)d_out;
    float* out_alloc = out_usage + (size_t)BM;

    const size_t smem = (size_t)M * sizeof(float);   // dynamic: uS only
    if (W == 4 && R == 8) {
        hipLaunchKernelGGL((fused_kernel<4, 8>), dim3(B), dim3(NT), smem, stream,
                           ww, fg, rw, prev, wgt, out_usage, out_alloc, B, W, R, M);
    } else {
        hipLaunchKernelGGL((fused_kernel<0, 0>), dim3(B), dim3(NT), smem, stream,
                           ww, fg, rw, prev, wgt, out_usage, out_alloc, B, W, R, M);
    }
}